// Round 9
// baseline (2424.386 us; speedup 1.0000x reference)
//
#include <hip/hip_runtime.h>
#include <math.h>

// ---------------------------------------------------------------------------
// ModelSpectral: hierarchical SAGEConv unpooling + MLP tail + QR(524288x2).
//
// R3: push-scatter hit f32-atomic ceiling -> CSR pull aggregation.
// R5: conv latency-bound -> 8-way pipelined neighbor loop.
// R6: CSR fill random 4B writes -> bucketed (L2-window) build.
// R7 analysis: conv gather at a random-line path ceiling (~1.3TB/s, FETCH =
//   64B x E); concurrency already 10x what Little's law needs -> only fewer/
//   cheaper requests help.
// R8: conv1 gathers R[inv[s]] DIRECTLY from the COARSE level (8MB at L0,
//   L2/L3-resident) instead of the materialized 64MB Q = R[inv]. Deletes
//   gather_kernel; exact same f32 arithmetic. conv2 (gather from 64MB conv1
//   output) unchanged -> next lever if still dominant.
//   Buffers: CSR scratch now lives in dead Q; conv1->Q, conv2->P (no swap).
//
// R9: resubmission of R8 unchanged (container infra failure, no data).
//
// All conv outputs stored POST-tanh. Falls back to R2 atomic-scatter path
// if ws too small.
// ---------------------------------------------------------------------------

static inline int imin(int a, int b) { return a < b ? a : b; }

__global__ void coarse_kernel(float* __restrict__ out, const float* __restrict__ Wl,
                              const float* __restrict__ Wr, const float* __restrict__ b) {
    int t = threadIdx.x;
    if (t < 64) {
        int i = t >> 5, c = t & 31;
        // x = eye(2); edges [[0,1],[1,0]]: agg[i] = x[1-i], deg=1
        out[i * 32 + c] = tanhf(Wl[(1 ^ i) * 32 + c] + Wr[i * 32 + c] + b[c]);
    }
}

__global__ void gather_kernel(float* __restrict__ out, const float* __restrict__ in,
                              const int* __restrict__ inv, int n) {
    int total = n * 32;
    int stride = gridDim.x * blockDim.x;
    for (int idx = blockIdx.x * blockDim.x + threadIdx.x; idx < total; idx += stride) {
        int i = idx >> 5, j = idx & 31;
        out[idx] = in[inv[i] * 32 + j];
    }
}

// ---------------- bucketed CSR build ----------------
// bucket = dst >> 10 (1024 dsts per bucket), NB = ceil(n/1024) <= 512.

// A: per-block bucket histogram -> gh[b*G + blk]  (bucket-major for scan)
__global__ void bkt_hist_kernel(int* __restrict__ gh, const int* __restrict__ dst,
                                int E, int NB, int G) {
    __shared__ int cnt[512];
    for (int t = threadIdx.x; t < NB; t += blockDim.x) cnt[t] = 0;
    __syncthreads();
    int stride = G * blockDim.x;
    for (int e = blockIdx.x * blockDim.x + threadIdx.x; e < E; e += stride)
        atomicAdd(&cnt[dst[e] >> 10], 1);
    __syncthreads();
    for (int t = threadIdx.x; t < NB; t += blockDim.x) gh[t * G + blockIdx.x] = cnt[t];
}

// exclusive scan, 1024 elems per block (Hillis-Steele in LDS)
__global__ void scan1_kernel(int* __restrict__ a, int* __restrict__ part, int n) {
    __shared__ int s[1024];
    int t = threadIdx.x, i = blockIdx.x * 1024 + t;
    int v = (i < n) ? a[i] : 0;
    s[t] = v;
    __syncthreads();
    for (int off = 1; off < 1024; off <<= 1) {
        int add = (t >= off) ? s[t - off] : 0;
        __syncthreads();
        s[t] += add;
        __syncthreads();
    }
    if (i < n) a[i] = s[t] - v;             // exclusive
    if (t == 1023) part[blockIdx.x] = s[t]; // block total
}

__global__ void scan2_kernel(int* __restrict__ part, int nb) {
    __shared__ int s[1024];
    int t = threadIdx.x;
    int v = (t < nb) ? part[t] : 0;
    s[t] = v;
    __syncthreads();
    for (int off = 1; off < 1024; off <<= 1) {
        int add = (t >= off) ? s[t - off] : 0;
        __syncthreads();
        s[t] += add;
        __syncthreads();
    }
    if (t < nb) part[t] = s[t] - v;         // exclusive
}

__global__ void scan3_kernel(int* __restrict__ a, const int* __restrict__ part, int n) {
    int i = blockIdx.x * 1024 + threadIdx.x;
    if (i < n && blockIdx.x > 0) a[i] += part[blockIdx.x];
}

// C: partition edges into part[]: packed (src<<10)|dst_local.
__global__ void bkt_part_kernel(int* __restrict__ part, const int* __restrict__ gh,
                                const int* __restrict__ edges, int E, int NB, int G) {
    __shared__ int cur[512];
    const int* __restrict__ src = edges;
    const int* __restrict__ dst = edges + E;
    for (int t = threadIdx.x; t < NB; t += blockDim.x) cur[t] = gh[t * G + blockIdx.x];
    __syncthreads();
    int stride = G * blockDim.x;
    for (int e = blockIdx.x * blockDim.x + threadIdx.x; e < E; e += stride) {
        int d = dst[e];
        int b = d >> 10;
        int p = atomicAdd(&cur[b], 1);
        part[p] = (src[e] << 10) | (d & 1023);
    }
}

// D: per-bucket local fill. Writes off[d] (END convention) and csr[] within
// the bucket's contiguous ~64KB L2-resident window.
__global__ void __launch_bounds__(1024)
bkt_fill_kernel(int* __restrict__ csr, int* __restrict__ off,
                const int* __restrict__ part, const int* __restrict__ gh,
                int E, int n, int NB, int G) {
    __shared__ int cnt[1024], s[1024];
    int b = blockIdx.x, t = threadIdx.x;
    int beg = gh[b * G];                          // bucket base (scanned)
    int endp = (b + 1 < NB) ? gh[(b + 1) * G] : E;
    cnt[t] = 0;
    __syncthreads();
    for (int i = beg + t; i < endp; i += 1024)
        atomicAdd(&cnt[part[i] & 1023], 1);
    __syncthreads();
    int v = cnt[t];
    s[t] = v;
    __syncthreads();
    for (int o = 1; o < 1024; o <<= 1) {
        int add = (t >= o) ? s[t - o] : 0;
        __syncthreads();
        s[t] += add;
        __syncthreads();
    }
    int d = b * 1024 + t;
    if (d < n) off[d] = beg + s[t];               // inclusive end of dst d
    cnt[t] = beg + s[t] - v;                      // global start cursor
    __syncthreads();
    for (int i = beg + t; i < endp; i += 1024) {
        int pv = part[i];
        int p = atomicAdd(&cnt[pv & 1023], 1);
        csr[p] = pv >> 10;
    }
}

// conv1 variant with implicit unpool: x[i] := R[inv[i]] (R = coarse level,
// small & cache-resident). out[d] = tanh(mean_s R[inv[s]]@Wl + R[inv[d]]@Wr + b)
__global__ void __launch_bounds__(256)
conv_ind_kernel(float* __restrict__ out, const float* __restrict__ R,
                const int* __restrict__ inv,
                const int* __restrict__ csr, const int* __restrict__ off,
                const float* __restrict__ Wl, const float* __restrict__ Wr,
                const float* __restrict__ b, int n) {
    __shared__ float sWl[1024], sWr[1024], sb[32];
    for (int t = threadIdx.x; t < 1024; t += blockDim.x) { sWl[t] = Wl[t]; sWr[t] = Wr[t]; }
    if (threadIdx.x < 32) sb[threadIdx.x] = b[threadIdx.x];
    __syncthreads();
    int lane = threadIdx.x & 31;
    int grp = threadIdx.x >> 5;
    int rstride = gridDim.x * 8;
    for (int row = blockIdx.x * 8 + grp; row < n; row += rstride) {
        int end = off[row];
        int start = (row == 0) ? 0 : off[row - 1];
        float acc = 0.f;
        int i = start;
        for (; i + 8 <= end; i += 8) {
            int s0 = csr[i + 0], s1 = csr[i + 1], s2 = csr[i + 2], s3 = csr[i + 3];
            int s4 = csr[i + 4], s5 = csr[i + 5], s6 = csr[i + 6], s7 = csr[i + 7];
            int a0 = inv[s0], a1 = inv[s1], a2 = inv[s2], a3 = inv[s3];
            int a4 = inv[s4], a5 = inv[s5], a6 = inv[s6], a7 = inv[s7];
            float v0 = R[(size_t)a0 * 32 + lane];
            float v1 = R[(size_t)a1 * 32 + lane];
            float v2 = R[(size_t)a2 * 32 + lane];
            float v3 = R[(size_t)a3 * 32 + lane];
            float v4 = R[(size_t)a4 * 32 + lane];
            float v5 = R[(size_t)a5 * 32 + lane];
            float v6 = R[(size_t)a6 * 32 + lane];
            float v7 = R[(size_t)a7 * 32 + lane];
            acc += ((v0 + v1) + (v2 + v3)) + ((v4 + v5) + (v6 + v7));
        }
        for (; i + 2 <= end; i += 2) {
            int s0 = csr[i], s1 = csr[i + 1];
            int a0 = inv[s0], a1 = inv[s1];
            float v0 = R[(size_t)a0 * 32 + lane];
            float v1 = R[(size_t)a1 * 32 + lane];
            acc += v0 + v1;
        }
        if (i < end) acc += R[(size_t)inv[csr[i]] * 32 + lane];

        float am = acc * (1.f / fmaxf((float)(end - start), 1.f));
        float xv = R[(size_t)inv[row] * 32 + lane];
        float o = sb[lane];
#pragma unroll
        for (int k = 0; k < 32; ++k) {
            float a = __shfl(am, k, 32);
            float t = __shfl(xv, k, 32);
            o += a * sWl[k * 32 + lane] + t * sWr[k * 32 + lane];
        }
        out[(size_t)row * 32 + lane] = tanhf(o);
    }
}

// conv2: direct x (fine level). out[d] = tanh(mean_s x[s]@Wl + x[d]@Wr + b)
__global__ void __launch_bounds__(256)
conv_csr_kernel(float* __restrict__ out, const float* __restrict__ x,
                const int* __restrict__ csr, const int* __restrict__ off,
                const float* __restrict__ Wl, const float* __restrict__ Wr,
                const float* __restrict__ b, int n) {
    __shared__ float sWl[1024], sWr[1024], sb[32];
    for (int t = threadIdx.x; t < 1024; t += blockDim.x) { sWl[t] = Wl[t]; sWr[t] = Wr[t]; }
    if (threadIdx.x < 32) sb[threadIdx.x] = b[threadIdx.x];
    __syncthreads();
    int lane = threadIdx.x & 31;
    int grp = threadIdx.x >> 5;
    int rstride = gridDim.x * 8;
    for (int row = blockIdx.x * 8 + grp; row < n; row += rstride) {
        int end = off[row];
        int start = (row == 0) ? 0 : off[row - 1];
        float acc = 0.f;
        int i = start;
        for (; i + 8 <= end; i += 8) {
            int s0 = csr[i + 0], s1 = csr[i + 1], s2 = csr[i + 2], s3 = csr[i + 3];
            int s4 = csr[i + 4], s5 = csr[i + 5], s6 = csr[i + 6], s7 = csr[i + 7];
            float v0 = x[(size_t)s0 * 32 + lane];
            float v1 = x[(size_t)s1 * 32 + lane];
            float v2 = x[(size_t)s2 * 32 + lane];
            float v3 = x[(size_t)s3 * 32 + lane];
            float v4 = x[(size_t)s4 * 32 + lane];
            float v5 = x[(size_t)s5 * 32 + lane];
            float v6 = x[(size_t)s6 * 32 + lane];
            float v7 = x[(size_t)s7 * 32 + lane];
            acc += ((v0 + v1) + (v2 + v3)) + ((v4 + v5) + (v6 + v7));
        }
        for (; i + 2 <= end; i += 2) {
            int s0 = csr[i], s1 = csr[i + 1];
            float v0 = x[(size_t)s0 * 32 + lane];
            float v1 = x[(size_t)s1 * 32 + lane];
            acc += v0 + v1;
        }
        if (i < end) acc += x[(size_t)csr[i] * 32 + lane];

        float am = acc * (1.f / fmaxf((float)(end - start), 1.f));
        float xv = x[(size_t)row * 32 + lane];
        float o = sb[lane];
#pragma unroll
        for (int k = 0; k < 32; ++k) {
            float a = __shfl(am, k, 32);
            float t = __shfl(xv, k, 32);
            o += a * sWl[k * 32 + lane] + t * sWr[k * 32 + lane];
        }
        out[(size_t)row * 32 + lane] = tanhf(o);
    }
}

// ---------------- fallback (R2 atomic-scatter path) ----------------
__global__ void deg_kernel(float* __restrict__ deg, const int* __restrict__ dst, int E) {
    int stride = gridDim.x * blockDim.x;
    for (int e = blockIdx.x * blockDim.x + threadIdx.x; e < E; e += stride)
        unsafeAtomicAdd(&deg[dst[e]], 1.0f);
}

__global__ void invdeg_kernel(float* __restrict__ deg, int n) {
    int stride = gridDim.x * blockDim.x;
    for (int i = blockIdx.x * blockDim.x + threadIdx.x; i < n; i += stride)
        deg[i] = 1.0f / fmaxf(deg[i], 1.0f);
}

__global__ void scatter_kernel(float* __restrict__ agg, const float* __restrict__ x,
                               const int* __restrict__ edges, int E) {
    const int* __restrict__ src = edges;
    const int* __restrict__ dst = edges + E;
    int total = E * 32;
    int stride = gridDim.x * blockDim.x;
    for (int idx = blockIdx.x * blockDim.x + threadIdx.x; idx < total; idx += stride) {
        int e = idx >> 5, j = idx & 31;
        unsafeAtomicAdd(&agg[dst[e] * 32 + j], x[src[e] * 32 + j]);
    }
}

__global__ void dense_kernel(float* __restrict__ agg, const float* __restrict__ x,
                             const float* __restrict__ invdeg,
                             const float* __restrict__ Wl, const float* __restrict__ Wr,
                             const float* __restrict__ b, int n) {
    __shared__ float sWl[1024], sWr[1024], sb[32];
    for (int t = threadIdx.x; t < 1024; t += blockDim.x) { sWl[t] = Wl[t]; sWr[t] = Wr[t]; }
    if (threadIdx.x < 32) sb[threadIdx.x] = b[threadIdx.x];
    __syncthreads();
    int row = blockIdx.x * 8 + (threadIdx.x >> 5);
    int c = threadIdx.x & 31;
    if (row >= n) return;
    float av = agg[row * 32 + c] * invdeg[row];
    float xv = x[row * 32 + c];
    float acc = sb[c];
#pragma unroll
    for (int k = 0; k < 32; ++k) {
        float a = __shfl(av, k, 32);
        float t = __shfl(xv, k, 32);
        acc += a * sWl[k * 32 + c] + t * sWr[k * 32 + c];
    }
    agg[row * 32 + c] = tanhf(acc);
}

// ---------------- MLP tail + QR ----------------
// Wave-parallel fused MLP: 32 lanes per row, lane c owns feature c.
__global__ void __launch_bounds__(256)
mlp_kernel(float* __restrict__ y, const float* __restrict__ x,
           const float* __restrict__ W1, const float* __restrict__ b1,
           const float* __restrict__ W2, const float* __restrict__ b2,
           const float* __restrict__ W3, const float* __restrict__ b3,
           const float* __restrict__ Wf, const float* __restrict__ bf,
           double* __restrict__ sums, int n) {
    __shared__ float sW1[512], sb1[16], sW2[512], sb2[32], sW3[1024], sb3[32], sWf[64], sbf[2];
    for (int t = threadIdx.x; t < 512; t += blockDim.x) { sW1[t] = W1[t]; sW2[t] = W2[t]; }
    for (int t = threadIdx.x; t < 1024; t += blockDim.x) sW3[t] = W3[t];
    if (threadIdx.x < 64) sWf[threadIdx.x] = Wf[threadIdx.x];
    if (threadIdx.x < 16) sb1[threadIdx.x] = b1[threadIdx.x];
    if (threadIdx.x < 32) { sb2[threadIdx.x] = b2[threadIdx.x]; sb3[threadIdx.x] = b3[threadIdx.x]; }
    if (threadIdx.x < 2) sbf[threadIdx.x] = bf[threadIdx.x];
    __syncthreads();

    int lane = threadIdx.x & 31;
    int grp = threadIdx.x >> 5;
    double la = 0.0, lab = 0.0, lb = 0.0;
    int rstride = gridDim.x * 8;
    for (int row = blockIdx.x * 8 + grp; row < n; row += rstride) {
        float xv = x[(size_t)row * 32 + lane];
        float h1 = sb1[lane & 15];
#pragma unroll
        for (int k = 0; k < 32; ++k)
            h1 += __shfl(xv, k, 32) * sW1[k * 16 + (lane & 15)];
        float t1 = tanhf(h1);
        float h2 = sb2[lane];
#pragma unroll
        for (int k = 0; k < 16; ++k)
            h2 += __shfl(t1, k, 32) * sW2[k * 32 + lane];
        float t2 = tanhf(h2);
        float h3 = sb3[lane];
#pragma unroll
        for (int k = 0; k < 32; ++k)
            h3 += __shfl(t2, k, 32) * sW3[k * 32 + lane];
        float t3 = tanhf(h3);
        float p0 = t3 * sWf[lane * 2];
        float p1 = t3 * sWf[lane * 2 + 1];
#pragma unroll
        for (int off = 16; off > 0; off >>= 1) {
            p0 += __shfl_xor(p0, off, 32);
            p1 += __shfl_xor(p1, off, 32);
        }
        if (lane == 0) {
            float y0 = p0 + sbf[0], y1 = p1 + sbf[1];
            y[row * 2] = y0;
            y[row * 2 + 1] = y1;
            la += (double)y0 * (double)y0;
            lab += (double)y0 * (double)y1;
            lb += (double)y1 * (double)y1;
        }
    }
#pragma unroll
    for (int off = 32; off > 0; off >>= 1) {
        la += __shfl_down(la, off);
        lab += __shfl_down(lab, off);
        lb += __shfl_down(lb, off);
    }
    __shared__ double red[4][3];
    int wid = threadIdx.x >> 6;
    if ((threadIdx.x & 63) == 0) { red[wid][0] = la; red[wid][1] = lab; red[wid][2] = lb; }
    __syncthreads();
    if (threadIdx.x == 0) {
        double ta = 0, tb = 0, tc = 0;
        for (int w = 0; w < 4; ++w) { ta += red[w][0]; tb += red[w][1]; tc += red[w][2]; }
        unsafeAtomicAdd(&sums[0], ta);
        unsafeAtomicAdd(&sums[1], tb);
        unsafeAtomicAdd(&sums[2], tc);
    }
}

// LAPACK (geqrf/orgqr) Householder sign convention for 2-column QR.
__global__ void qr_scalar_kernel(float* __restrict__ scal, const double* __restrict__ sums,
                                 const float* __restrict__ y) {
    double saa = sums[0], sab = sums[1], sbb = sums[2];
    double a0 = (double)y[0], b0 = (double)y[1];
    double a1 = (double)y[2], b1v = (double)y[3];
    double na = sqrt(saa);
    double beta1 = (a0 >= 0.0) ? -na : na;       // beta = -sign(alpha)*||a||
    double R12 = sab / beta1;                    // (H1 b)[0] = q1.b
    double v2 = sbb - R12 * R12;                 // ||b - R12 q1||^2
    if (v2 < 0.0) v2 = 0.0;
    double nb = sqrt(v2);
    double denom = a0 - beta1;                   // nonzero: a0 + sign(a0)||a||
    double tau1 = (beta1 - a0) / beta1;
    double u1b = b0 + (sab - a0 * b0) / denom;   // v1 . b  (v1[0]=1)
    double y1h = b1v - tau1 * u1b * (a1 / denom);// (H1 b)[1] -> pivot of reflector 2
    double beta2 = (y1h >= 0.0) ? -nb : nb;
    scal[0] = (float)(1.0 / beta1);
    scal[1] = (float)R12;
    scal[2] = (float)(1.0 / beta2);
}

__global__ void q_kernel(float* __restrict__ y, const float* __restrict__ scal, int n) {
    float invb1 = scal[0], R12 = scal[1], invb2 = scal[2];
    int stride = gridDim.x * blockDim.x;
    float2* p = (float2*)y;
    for (int i = blockIdx.x * blockDim.x + threadIdx.x; i < n; i += stride) {
        float2 v = p[i];
        float qa = v.x * invb1;
        float qb = (v.y - R12 * qa) * invb2;
        p[i] = make_float2(qa, qb);
    }
}

extern "C" void kernel_launch(void* const* d_in, const int* in_sizes, int n_in,
                              void* d_out, int out_size, void* d_ws, size_t ws_size,
                              hipStream_t stream) {
    const int* edges[6];
    const int* inv[6];
    int nl[6], El[6];
    for (int l = 0; l < 6; ++l) {
        edges[l] = (const int*)d_in[2 * l];
        inv[l] = (const int*)d_in[2 * l + 1];
        El[l] = in_sizes[2 * l] / 2;
        nl[l] = in_sizes[2 * l + 1];
    }
    const float* Wc_l = (const float*)d_in[13];
    const float* Wc_r = (const float*)d_in[14];
    const float* bc = (const float*)d_in[15];
    const float* Wp_l[2] = {(const float*)d_in[16], (const float*)d_in[19]};
    const float* Wp_r[2] = {(const float*)d_in[17], (const float*)d_in[20]};
    const float* bp[2] = {(const float*)d_in[18], (const float*)d_in[21]};
    const float* W1 = (const float*)d_in[22];
    const float* b1 = (const float*)d_in[23];
    const float* W2 = (const float*)d_in[24];
    const float* b2 = (const float*)d_in[25];
    const float* W3 = (const float*)d_in[26];
    const float* b3 = (const float*)d_in[27];
    const float* Wf = (const float*)d_in[28];
    const float* bf = (const float*)d_in[29];

    char* ws = (char*)d_ws;
    // layout: bufA 64MB (P) | bufB 64MB (Q) | csr 32MB | off 2MB | sums | scal
    // (part/gh/spart live inside the dead Q buffer during CSR build)
    const size_t OFF_CSR = 134217728;
    const size_t OFF_OFF = 167772160;
    const size_t OFF_SUMS = 169873920;
    const size_t OFF_SCAL = 169873952;
    const size_t NEED_CSR = 169874432;

    bool use_csr = ws_size >= NEED_CSR;

    float* bufA = (float*)ws;
    float* bufB = (float*)(ws + 67108864);
    double* sums;
    float* scal;

    float* P = bufA;  // holds previous-level post-tanh result (R)
    float* Q = bufB;
    coarse_kernel<<<1, 64, 0, stream>>>(P, Wc_l, Wc_r, bc);

    if (use_csr) {
        int* csr = (int*)(ws + OFF_CSR);
        int* off = (int*)(ws + OFF_OFF);
        sums = (double*)(ws + OFF_SUMS);
        scal = (float*)(ws + OFF_SCAL);

        for (int l = 5; l >= 0; --l) {
            int n = nl[l], E = El[l];
            int NB = (n + 1023) / 1024;                 // <= 512
            int G = imin(256, (E + 4095) / 4096);       // partition blocks
            // CSR-build scratch in the DEAD Q buffer (consumed by bkt_fill
            // before conv1 writes its output into Q)
            int* part = (int*)Q;
            int* gh = part + E;
            int* spart = gh + NB * G;
            bkt_hist_kernel<<<G, 256, 0, stream>>>(gh, edges[l] + E, E, NB, G);
            int sn = NB * G;
            int nsb = (sn + 1023) / 1024;
            scan1_kernel<<<nsb, 1024, 0, stream>>>(gh, spart, sn);
            scan2_kernel<<<1, 1024, 0, stream>>>(spart, nsb);
            scan3_kernel<<<nsb, 1024, 0, stream>>>(gh, spart, sn);
            bkt_part_kernel<<<G, 256, 0, stream>>>(part, gh, edges[l], E, NB, G);
            bkt_fill_kernel<<<NB, 1024, 0, stream>>>(csr, off, part, gh, E, n, NB, G);
            int cgrid = imin((n + 7) / 8, 65536);
            // conv1: implicit unpool, reads coarse R (=P, cache-resident) -> out Q
            conv_ind_kernel<<<cgrid, 256, 0, stream>>>(
                Q, P, inv[l], csr, off, Wp_l[0], Wp_r[0], bp[0], n);
            // conv2: direct x=Q -> out P (P dead after conv1 consumed it)
            conv_csr_kernel<<<cgrid, 256, 0, stream>>>(
                P, Q, csr, off, Wp_l[1], Wp_r[1], bp[1], n);
            // result in P; no swap needed
        }
    } else {
        // fallback: R2 atomic-scatter path
        float* deg = (float*)(ws + 134217728);
        sums = (double*)(ws + 136314880);
        scal = (float*)(ws + 136315008);
        for (int l = 5; l >= 0; --l) {
            int n = nl[l], E = El[l];
            gather_kernel<<<imin((n * 32 + 255) / 256, 65536), 256, 0, stream>>>(Q, P, inv[l], n);
            hipMemsetAsync(deg, 0, (size_t)n * sizeof(float), stream);
            deg_kernel<<<imin((E + 255) / 256, 32768), 256, 0, stream>>>(deg, edges[l] + E, E);
            invdeg_kernel<<<imin((n + 255) / 256, 8192), 256, 0, stream>>>(deg, n);
            hipMemsetAsync(P, 0, (size_t)n * 32 * sizeof(float), stream);
            scatter_kernel<<<imin((E * 32 + 255) / 256, 65536), 256, 0, stream>>>(P, Q, edges[l], E);
            dense_kernel<<<(n + 7) / 8, 256, 0, stream>>>(P, Q, deg, Wp_l[0], Wp_r[0], bp[0], n);
            hipMemsetAsync(Q, 0, (size_t)n * 32 * sizeof(float), stream);
            scatter_kernel<<<imin((E * 32 + 255) / 256, 65536), 256, 0, stream>>>(Q, P, edges[l], E);
            dense_kernel<<<(n + 7) / 8, 256, 0, stream>>>(Q, P, deg, Wp_l[1], Wp_r[1], bp[1], n);
            float* t = P; P = Q; Q = t;
        }
    }

    hipMemsetAsync(sums, 0, 3 * sizeof(double), stream);
    mlp_kernel<<<4096, 256, 0, stream>>>((float*)d_out, P, W1, b1, W2, b2, W3, b3, Wf, bf,
                                         sums, nl[0]);
    qr_scalar_kernel<<<1, 1, 0, stream>>>(scal, sums, (const float*)d_out);
    q_kernel<<<imin((nl[0] + 255) / 256, 4096), 256, 0, stream>>>((float*)d_out, scal, nl[0]);
}